// Round 4
// baseline (338.950 us; speedup 1.0000x reference)
//
#include <hip/hip_runtime.h>
#include <hip/hip_bf16.h>

// Problem constants
#define DIMD   1024
#define BATCH  4
#define SEQ    4096
#define NTOK   (BATCH * SEQ)   // 16384
#define CHUNK  64              // recurrence chunk length
#define NCHUNK (SEQ / CHUNK)   // 64

// GEMM tiling (m97 structure)
#define BM 128
#define BN 128
#define BK 32

typedef unsigned short ushort_t;
typedef __attribute__((ext_vector_type(8))) __bf16   bf16x8;
typedef __attribute__((ext_vector_type(4))) float    f32x4;
typedef __attribute__((ext_vector_type(8))) ushort_t u16x8;

__device__ __forceinline__ float b2f(ushort_t u) {
    union { unsigned int i; float f; } x;
    x.i = ((unsigned int)u) << 16;
    return x.f;
}

__device__ __forceinline__ ushort_t f2b(float f) {
    union { float f; unsigned int i; } x;
    x.f = f;
    unsigned int r = x.i + 0x7fffu + ((x.i >> 16) & 1u);  // RNE
    return (ushort_t)(r >> 16);
}

// ---------------------------------------------------------------------------
// f32 -> bf16, 8 elem/thread, 16B stores.
// ---------------------------------------------------------------------------
__global__ __launch_bounds__(256)
void conv_f2b(const float* __restrict__ src, ushort_t* __restrict__ dst, int n8)
{
    const int i = blockIdx.x * 256 + threadIdx.x;
    if (i >= n8) return;
    const float4* s4 = (const float4*)src;
    const float4 a = s4[i * 2];
    const float4 b = s4[i * 2 + 1];
    u16x8 o;
    o[0] = f2b(a.x); o[1] = f2b(a.y); o[2] = f2b(a.z); o[3] = f2b(a.w);
    o[4] = f2b(b.x); o[5] = f2b(b.y); o[6] = f2b(b.z); o[7] = f2b(b.w);
    *(u16x8*)(dst + (size_t)i * 8) = o;
}

// All 4 weight matrices in one launch; blockIdx.y selects the matrix.
// dst holds 4 contiguous 1024x1024 bf16 matrices in order Wk,Wv,Wr,Wo.
__global__ __launch_bounds__(256)
void conv_w(const float* __restrict__ W0, const float* __restrict__ W1,
            const float* __restrict__ W2, const float* __restrict__ W3,
            ushort_t* __restrict__ dst)
{
    const int m = blockIdx.y;
    const float* src = (m == 0) ? W0 : (m == 1) ? W1 : (m == 2) ? W2 : W3;
    const int i = blockIdx.x * 256 + threadIdx.x;     // 0 .. 131071
    const float4* s4 = (const float4*)src;
    const float4 a = s4[i * 2];
    const float4 b = s4[i * 2 + 1];
    u16x8 o;
    o[0] = f2b(a.x); o[1] = f2b(a.y); o[2] = f2b(a.z); o[3] = f2b(a.w);
    o[4] = f2b(b.x); o[5] = f2b(b.y); o[6] = f2b(b.z); o[7] = f2b(b.w);
    *(u16x8*)(dst + (size_t)m * DIMD * DIMD + (size_t)i * 8) = o;
}

// ---------------------------------------------------------------------------
// Fused 3-projection GEMM: one A staging, 3 B tiles, 3 accumulators.
// Outputs kv = k*v (bf16) and r = sigmoid(.) (bf16).
// ---------------------------------------------------------------------------
__global__ __launch_bounds__(256, 2)
void gemm_kvr(const ushort_t* __restrict__ A,
              const ushort_t* __restrict__ Wk,
              const ushort_t* __restrict__ Wv,
              const ushort_t* __restrict__ Wr,
              ushort_t* __restrict__ Okv,
              ushort_t* __restrict__ Or)
{
    __shared__ __align__(16) ushort_t As[BM * BK];
    __shared__ __align__(16) ushort_t Bk[BN * BK];
    __shared__ __align__(16) ushort_t Bv[BN * BK];
    __shared__ __align__(16) ushort_t Br[BN * BK];

    const int tid  = threadIdx.x;
    const int lane = tid & 63;
    const int wv   = tid >> 6;
    const int wr   = wv >> 1;
    const int wc   = wv & 1;
    const int lrow = lane & 15;
    const int kq   = lane >> 4;

    const int row0 = blockIdx.x * BM;
    const int e0   = blockIdx.y * BN;

    f32x4 ak[4][4], av[4][4], ar[4][4];
#pragma unroll
    for (int i = 0; i < 4; i++)
#pragma unroll
        for (int j = 0; j < 4; j++) {
            ak[i][j] = f32x4{0.f, 0.f, 0.f, 0.f};
            av[i][j] = f32x4{0.f, 0.f, 0.f, 0.f};
            ar[i][j] = f32x4{0.f, 0.f, 0.f, 0.f};
        }

    for (int kt = 0; kt < DIMD / BK; ++kt) {
        const int k0 = kt * BK;

        __syncthreads();

        // 4 tiles x 8 KB; per-wave LDS dest = uniform base + lane*16.
#pragma unroll
        for (int it = 0; it < 2; ++it) {
            const int chunk = tid + it * 256;          // 0..511
            const int r = chunk >> 2;
            const int c = (chunk & 3) << 3;
            const ushort_t* ga = A  + (size_t)(row0 + r) * DIMD + k0 + c;
            const ushort_t* gk = Wk + (size_t)(e0 + r) * DIMD + k0 + c;
            const ushort_t* gv = Wv + (size_t)(e0 + r) * DIMD + k0 + c;
            const ushort_t* gr = Wr + (size_t)(e0 + r) * DIMD + k0 + c;
            __builtin_amdgcn_global_load_lds(
                (__attribute__((address_space(1))) void*)ga,
                (__attribute__((address_space(3))) void*)((char*)As + chunk * 16),
                16, 0, 0);
            __builtin_amdgcn_global_load_lds(
                (__attribute__((address_space(1))) void*)gk,
                (__attribute__((address_space(3))) void*)((char*)Bk + chunk * 16),
                16, 0, 0);
            __builtin_amdgcn_global_load_lds(
                (__attribute__((address_space(1))) void*)gv,
                (__attribute__((address_space(3))) void*)((char*)Bv + chunk * 16),
                16, 0, 0);
            __builtin_amdgcn_global_load_lds(
                (__attribute__((address_space(1))) void*)gr,
                (__attribute__((address_space(3))) void*)((char*)Br + chunk * 16),
                16, 0, 0);
        }

        __syncthreads();

        bf16x8 af[4], bk4[4], bv4[4], br4[4];
#pragma unroll
        for (int i = 0; i < 4; i++)
            af[i] = *(const bf16x8*)(As + (wr * 64 + i * 16 + lrow) * BK + kq * 8);
#pragma unroll
        for (int j = 0; j < 4; j++) {
            bk4[j] = *(const bf16x8*)(Bk + (wc * 64 + j * 16 + lrow) * BK + kq * 8);
            bv4[j] = *(const bf16x8*)(Bv + (wc * 64 + j * 16 + lrow) * BK + kq * 8);
            br4[j] = *(const bf16x8*)(Br + (wc * 64 + j * 16 + lrow) * BK + kq * 8);
        }

#pragma unroll
        for (int i = 0; i < 4; i++)
#pragma unroll
            for (int j = 0; j < 4; j++) {
                ak[i][j] = __builtin_amdgcn_mfma_f32_16x16x32_bf16(
                    af[i], bk4[j], ak[i][j], 0, 0, 0);
                av[i][j] = __builtin_amdgcn_mfma_f32_16x16x32_bf16(
                    af[i], bv4[j], av[i][j], 0, 0, 0);
                ar[i][j] = __builtin_amdgcn_mfma_f32_16x16x32_bf16(
                    af[i], br4[j], ar[i][j], 0, 0, 0);
            }
    }

    // Epilogue. C/D layout: col = lane&15, row = (lane>>4)*4 + reg.
#pragma unroll
    for (int i = 0; i < 4; i++)
#pragma unroll
        for (int j = 0; j < 4; j++)
#pragma unroll
            for (int r = 0; r < 4; r++) {
                const int row = row0 + wr * 64 + i * 16 + kq * 4 + r;
                const int col = e0 + wc * 64 + j * 16 + lrow;
                const size_t o = (size_t)row * DIMD + col;
                Okv[o] = f2b(ak[i][j][r] * av[i][j][r]);
                Or[o]  = f2b(1.f / (1.f + __expf(-ar[i][j][r])));
            }
}

// ---------------------------------------------------------------------------
// Single GEMM (final projection): C[n,e] = sum_d A[n,d] * W[e,d], f32 out.
// ---------------------------------------------------------------------------
__global__ __launch_bounds__(256, 2)
void gemm_bt(const ushort_t* __restrict__ A,
             const ushort_t* __restrict__ W,
             float* __restrict__ Of)
{
    __shared__ __align__(16) ushort_t As[BM * BK];
    __shared__ __align__(16) ushort_t Bs[BN * BK];

    const int tid  = threadIdx.x;
    const int lane = tid & 63;
    const int wv   = tid >> 6;
    const int wr   = wv >> 1;
    const int wc   = wv & 1;
    const int lrow = lane & 15;
    const int kq   = lane >> 4;

    const int row0 = blockIdx.x * BM;
    const int e0   = blockIdx.y * BN;

    f32x4 acc[4][4];
#pragma unroll
    for (int i = 0; i < 4; i++)
#pragma unroll
        for (int j = 0; j < 4; j++)
            acc[i][j] = f32x4{0.f, 0.f, 0.f, 0.f};

    for (int kt = 0; kt < DIMD / BK; ++kt) {
        const int k0 = kt * BK;

        __syncthreads();

#pragma unroll
        for (int it = 0; it < 2; ++it) {
            const int chunk = tid + it * 256;
            const int r = chunk >> 2;
            const int c = (chunk & 3) << 3;
            const ushort_t* ga = A + (size_t)(row0 + r) * DIMD + k0 + c;
            const ushort_t* gb = W + (size_t)(e0 + r) * DIMD + k0 + c;
            __builtin_amdgcn_global_load_lds(
                (__attribute__((address_space(1))) void*)ga,
                (__attribute__((address_space(3))) void*)((char*)As + chunk * 16),
                16, 0, 0);
            __builtin_amdgcn_global_load_lds(
                (__attribute__((address_space(1))) void*)gb,
                (__attribute__((address_space(3))) void*)((char*)Bs + chunk * 16),
                16, 0, 0);
        }

        __syncthreads();

        bf16x8 af[4], bfr[4];
#pragma unroll
        for (int i = 0; i < 4; i++)
            af[i] = *(const bf16x8*)(As + (wr * 64 + i * 16 + lrow) * BK + kq * 8);
#pragma unroll
        for (int j = 0; j < 4; j++)
            bfr[j] = *(const bf16x8*)(Bs + (wc * 64 + j * 16 + lrow) * BK + kq * 8);

#pragma unroll
        for (int i = 0; i < 4; i++)
#pragma unroll
            for (int j = 0; j < 4; j++)
                acc[i][j] = __builtin_amdgcn_mfma_f32_16x16x32_bf16(
                    af[i], bfr[j], acc[i][j], 0, 0, 0);
    }

#pragma unroll
    for (int i = 0; i < 4; i++)
#pragma unroll
        for (int j = 0; j < 4; j++)
#pragma unroll
            for (int r = 0; r < 4; r++) {
                const int row = row0 + wr * 64 + i * 16 + kq * 4 + r;
                const int col = e0 + wc * 64 + j * 16 + lrow;
                Of[(size_t)row * DIMD + col] = acc[i][j][r];
            }
}

// ---------------------------------------------------------------------------
// Pass 1: per-chunk weighted sums of kv. Thread per (b, chunk, d8): 8 d's.
// ---------------------------------------------------------------------------
__global__ __launch_bounds__(256)
void chunk_agg(const ushort_t* __restrict__ kvb,
               const float* __restrict__ td, float* __restrict__ cs)
{
    const int t  = blockIdx.x * 256 + threadIdx.x;   // 32768 threads
    const int d0 = (t & (DIMD / 8 - 1)) * 8;
    const int bc = t >> 7;
    const int c  = bc & (NCHUNK - 1);
    const int b  = bc >> 6;

    float decay[8], s[8];
#pragma unroll
    for (int j = 0; j < 8; j++) {
        decay[j] = __expf(-__expf(td[d0 + j]));
        s[j] = 0.f;
    }

    size_t off = ((size_t)b * SEQ + (size_t)c * CHUNK) * DIMD + d0;
#pragma unroll 8
    for (int i = 0; i < CHUNK; i++) {
        const u16x8 kv8 = *(const u16x8*)(kvb + off);
#pragma unroll
        for (int j = 0; j < 8; j++)
            s[j] = decay[j] * s[j] + b2f(kv8[j]);
        off += DIMD;
    }

    float* dst = cs + ((size_t)bc * DIMD + d0);
    *(float4*)(dst)     = float4{s[0], s[1], s[2], s[3]};
    *(float4*)(dst + 4) = float4{s[4], s[5], s[6], s[7]};
}

// ---------------------------------------------------------------------------
// Pass 2: scan across chunks, register-resident. Thread per (b, d).
// ---------------------------------------------------------------------------
__global__ __launch_bounds__(256)
void chunk_scan(float* __restrict__ cs, const float* __restrict__ td)
{
    const int idx = blockIdx.x * 256 + threadIdx.x;  // 4096 threads
    const int d = idx & (DIMD - 1);
    const int b = idx >> 10;

    const float w      = -__expf(td[d]);
    const float decayL = __expf(w * (float)CHUNK);

    float v[NCHUNK];
    const size_t base = ((size_t)b * NCHUNK) * DIMD + d;
#pragma unroll
    for (int c = 0; c < NCHUNK; c++)
        v[c] = cs[base + (size_t)c * DIMD];

    float st = 0.f;
#pragma unroll
    for (int c = 0; c < NCHUNK; c++) {
        const float sc = v[c];
        v[c] = st;
        st = decayL * st + sc;
    }

#pragma unroll
    for (int c = 0; c < NCHUNK; c++)
        cs[base + (size_t)c * DIMD] = v[c];
}

// ---------------------------------------------------------------------------
// Pass 3: out_pre = r*(state + eu*kv); state = decay*state + kv. 8 d's/thread.
// ---------------------------------------------------------------------------
__global__ __launch_bounds__(256)
void emit(const ushort_t* __restrict__ kvb, const ushort_t* __restrict__ rb,
          const float* __restrict__ td, const float* __restrict__ tf,
          const float* __restrict__ cs, ushort_t* __restrict__ op)
{
    const int t  = blockIdx.x * 256 + threadIdx.x;   // 32768 threads
    const int d0 = (t & (DIMD / 8 - 1)) * 8;
    const int bc = t >> 7;
    const int c  = bc & (NCHUNK - 1);
    const int b  = bc >> 6;

    float decay[8], eu[8], st[8];
#pragma unroll
    for (int j = 0; j < 8; j++) {
        decay[j] = __expf(-__expf(td[d0 + j]));
        eu[j]    = __expf(tf[d0 + j]);
    }
    const float* csp = cs + ((size_t)bc * DIMD + d0);
    const float4 s0 = *(const float4*)csp;
    const float4 s1 = *(const float4*)(csp + 4);
    st[0] = s0.x; st[1] = s0.y; st[2] = s0.z; st[3] = s0.w;
    st[4] = s1.x; st[5] = s1.y; st[6] = s1.z; st[7] = s1.w;

    size_t off = ((size_t)b * SEQ + (size_t)c * CHUNK) * DIMD + d0;
#pragma unroll 8
    for (int i = 0; i < CHUNK; i++) {
        const u16x8 kv8 = *(const u16x8*)(kvb + off);
        const u16x8 r8  = *(const u16x8*)(rb + off);
        u16x8 o8;
#pragma unroll
        for (int j = 0; j < 8; j++) {
            const float kv = b2f(kv8[j]);
            o8[j] = f2b(b2f(r8[j]) * (st[j] + eu[j] * kv));
            st[j] = decay[j] * st[j] + kv;
        }
        *(u16x8*)(op + off) = o8;
        off += DIMD;
    }
}

// ---------------------------------------------------------------------------
// ws: xb/pbuf 32 MiB + weights 8 MiB + cs 1 MiB = 41 MiB.
// d_out (64 MiB f32) doubles as kvb+rb scratch (dead before final GEMM).
// ---------------------------------------------------------------------------
extern "C" void kernel_launch(void* const* d_in, const int* in_sizes, int n_in,
                              void* d_out, int out_size, void* d_ws, size_t ws_size,
                              hipStream_t stream)
{
    const float* x  = (const float*)d_in[0];
    const float* Wk = (const float*)d_in[1];
    const float* Wv = (const float*)d_in[2];
    const float* Wr = (const float*)d_in[3];
    const float* Wo = (const float*)d_in[4];
    const float* td = (const float*)d_in[5];
    const float* tf = (const float*)d_in[6];

    ushort_t* xb  = (ushort_t*)d_ws;                       // 32 MiB; reused as pbuf
    ushort_t* Wb  = xb + (size_t)NTOK * DIMD;              // 8 MiB (4 matrices)
    ushort_t* Wkb = Wb;
    ushort_t* Wvb = Wb + (size_t)DIMD * DIMD;
    ushort_t* Wrb = Wb + 2 * (size_t)DIMD * DIMD;
    ushort_t* Wob = Wb + 3 * (size_t)DIMD * DIMD;
    float*    cs  = (float*)(Wb + 4 * (size_t)DIMD * DIMD); // 1 MiB
    ushort_t* pbuf = xb;

    ushort_t* kvb = (ushort_t*)d_out;                      // 32 MiB scratch
    ushort_t* rb  = kvb + (size_t)NTOK * DIMD;             // 32 MiB scratch
    float*    out = (float*)d_out;

    // 0) conversions
    conv_f2b<<<NTOK * DIMD / 8 / 256, 256, 0, stream>>>(x, xb, NTOK * DIMD / 8);
    conv_w<<<dim3(DIMD * DIMD / 8 / 256, 4), 256, 0, stream>>>(Wk, Wv, Wr, Wo, Wb);

    // 1) fused kv & r projections
    gemm_kvr<<<dim3(NTOK / BM, DIMD / BN), 256, 0, stream>>>(
        xb, Wkb, Wvb, Wrb, kvb, rb);

    // 2) per-chunk aggregates
    chunk_agg<<<BATCH * NCHUNK * (DIMD / 8) / 256, 256, 0, stream>>>(kvb, td, cs);

    // 3) scan over chunk boundaries
    chunk_scan<<<BATCH * DIMD / 256, 256, 0, stream>>>(cs, td);

    // 4) out_pre -> pbuf (xb region)
    emit<<<BATCH * NCHUNK * (DIMD / 8) / 256, 256, 0, stream>>>(
        kvb, rb, td, tf, cs, pbuf);

    // 5) out = out_pre @ Wo^T (f32 epilogue, overwrites d_out)
    gemm_bt<<<dim3(NTOK / BM, DIMD / BN), 256, 0, stream>>>(pbuf, Wob, out);
}

// Round 5
// 319.876 us; speedup vs baseline: 1.0596x; 1.0596x over previous
//
#include <hip/hip_runtime.h>
#include <hip/hip_bf16.h>

// Problem constants
#define DIMD   1024
#define BATCH  4
#define SEQ    4096
#define NTOK   (BATCH * SEQ)   // 16384
#define CHUNK  64              // recurrence chunk length
#define NCHUNK (SEQ / CHUNK)   // 64

// GEMM tiling
#define BM 128
#define BN 128     // final GEMM
#define BK 32
#define BNF 64     // fused kvr GEMM N-tile

typedef unsigned short ushort_t;
typedef __attribute__((ext_vector_type(8))) __bf16   bf16x8;
typedef __attribute__((ext_vector_type(4))) float    f32x4;
typedef __attribute__((ext_vector_type(8))) ushort_t u16x8;

__device__ __forceinline__ float b2f(ushort_t u) {
    union { unsigned int i; float f; } x;
    x.i = ((unsigned int)u) << 16;
    return x.f;
}

__device__ __forceinline__ ushort_t f2b(float f) {
    union { float f; unsigned int i; } x;
    x.f = f;
    unsigned int r = x.i + 0x7fffu + ((x.i >> 16) & 1u);  // RNE
    return (ushort_t)(r >> 16);
}

// ---------------------------------------------------------------------------
// f32 -> bf16, 8 elem/thread, 16B stores.
// ---------------------------------------------------------------------------
__global__ __launch_bounds__(256)
void conv_f2b(const float* __restrict__ src, ushort_t* __restrict__ dst, int n8)
{
    const int i = blockIdx.x * 256 + threadIdx.x;
    if (i >= n8) return;
    const float4* s4 = (const float4*)src;
    const float4 a = s4[i * 2];
    const float4 b = s4[i * 2 + 1];
    u16x8 o;
    o[0] = f2b(a.x); o[1] = f2b(a.y); o[2] = f2b(a.z); o[3] = f2b(a.w);
    o[4] = f2b(b.x); o[5] = f2b(b.y); o[6] = f2b(b.z); o[7] = f2b(b.w);
    *(u16x8*)(dst + (size_t)i * 8) = o;
}

// All 4 weight matrices in one launch; blockIdx.y selects the matrix.
__global__ __launch_bounds__(256)
void conv_w(const float* __restrict__ W0, const float* __restrict__ W1,
            const float* __restrict__ W2, const float* __restrict__ W3,
            ushort_t* __restrict__ dst)
{
    const int m = blockIdx.y;
    const float* src = (m == 0) ? W0 : (m == 1) ? W1 : (m == 2) ? W2 : W3;
    const int i = blockIdx.x * 256 + threadIdx.x;
    const float4* s4 = (const float4*)src;
    const float4 a = s4[i * 2];
    const float4 b = s4[i * 2 + 1];
    u16x8 o;
    o[0] = f2b(a.x); o[1] = f2b(a.y); o[2] = f2b(a.z); o[3] = f2b(a.w);
    o[4] = f2b(b.x); o[5] = f2b(b.y); o[6] = f2b(b.z); o[7] = f2b(b.w);
    *(u16x8*)(dst + (size_t)m * DIMD * DIMD + (size_t)i * 8) = o;
}

// ---------------------------------------------------------------------------
// Fused 3-projection GEMM, BM=128 x BNF=64. One A staging, 3 B tiles,
// 3 accumulator sets (4x2 each). Outputs kv = k*v (bf16), r = sigmoid (bf16),
// and per-chunk decay-weighted sums cs (f32) via in-register reduction:
// block rows = 2 whole 64-token chunks; wave wr owns one chunk.
// ---------------------------------------------------------------------------
__global__ __launch_bounds__(256, 2)
void gemm_kvr(const ushort_t* __restrict__ A,
              const ushort_t* __restrict__ Wk,
              const ushort_t* __restrict__ Wv,
              const ushort_t* __restrict__ Wr,
              const float* __restrict__ td,
              ushort_t* __restrict__ Okv,
              ushort_t* __restrict__ Or,
              float* __restrict__ cs)
{
    __shared__ __align__(16) ushort_t As[BM * BK];   // 8 KB
    __shared__ __align__(16) ushort_t Bk[BNF * BK];  // 4 KB
    __shared__ __align__(16) ushort_t Bv[BNF * BK];  // 4 KB
    __shared__ __align__(16) ushort_t Br[BNF * BK];  // 4 KB

    const int tid  = threadIdx.x;
    const int lane = tid & 63;
    const int wv   = tid >> 6;
    const int wr   = wv >> 1;         // row half (= chunk within block)
    const int wc   = wv & 1;          // col half (32 cols)
    const int lrow = lane & 15;
    const int kq   = lane >> 4;

    const int row0 = blockIdx.x * BM;
    const int e0   = blockIdx.y * BNF;

    f32x4 ak[4][2], av[4][2], ar[4][2];
#pragma unroll
    for (int i = 0; i < 4; i++)
#pragma unroll
        for (int j = 0; j < 2; j++) {
            ak[i][j] = f32x4{0.f, 0.f, 0.f, 0.f};
            av[i][j] = f32x4{0.f, 0.f, 0.f, 0.f};
            ar[i][j] = f32x4{0.f, 0.f, 0.f, 0.f};
        }

    for (int kt = 0; kt < DIMD / BK; ++kt) {
        const int k0 = kt * BK;

        __syncthreads();

        // A: 512 x 16B chunks (2/thread); each B: 256 chunks (1/thread).
#pragma unroll
        for (int it = 0; it < 2; ++it) {
            const int chunk = tid + it * 256;
            const int r = chunk >> 2;
            const int c = (chunk & 3) << 3;
            const ushort_t* ga = A + (size_t)(row0 + r) * DIMD + k0 + c;
            __builtin_amdgcn_global_load_lds(
                (__attribute__((address_space(1))) void*)ga,
                (__attribute__((address_space(3))) void*)((char*)As + chunk * 16),
                16, 0, 0);
        }
        {
            const int r = tid >> 2;                 // 0..63
            const int c = (tid & 3) << 3;
            const size_t go = (size_t)(e0 + r) * DIMD + k0 + c;
            __builtin_amdgcn_global_load_lds(
                (__attribute__((address_space(1))) void*)(Wk + go),
                (__attribute__((address_space(3))) void*)((char*)Bk + tid * 16),
                16, 0, 0);
            __builtin_amdgcn_global_load_lds(
                (__attribute__((address_space(1))) void*)(Wv + go),
                (__attribute__((address_space(3))) void*)((char*)Bv + tid * 16),
                16, 0, 0);
            __builtin_amdgcn_global_load_lds(
                (__attribute__((address_space(1))) void*)(Wr + go),
                (__attribute__((address_space(3))) void*)((char*)Br + tid * 16),
                16, 0, 0);
        }

        __syncthreads();

        bf16x8 af[4], bk4[2], bv4[2], br4[2];
#pragma unroll
        for (int i = 0; i < 4; i++)
            af[i] = *(const bf16x8*)(As + (wr * 64 + i * 16 + lrow) * BK + kq * 8);
#pragma unroll
        for (int j = 0; j < 2; j++) {
            const int bo = (wc * 32 + j * 16 + lrow) * BK + kq * 8;
            bk4[j] = *(const bf16x8*)(Bk + bo);
            bv4[j] = *(const bf16x8*)(Bv + bo);
            br4[j] = *(const bf16x8*)(Br + bo);
        }

#pragma unroll
        for (int i = 0; i < 4; i++)
#pragma unroll
            for (int j = 0; j < 2; j++) {
                ak[i][j] = __builtin_amdgcn_mfma_f32_16x16x32_bf16(
                    af[i], bk4[j], ak[i][j], 0, 0, 0);
                av[i][j] = __builtin_amdgcn_mfma_f32_16x16x32_bf16(
                    af[i], bv4[j], av[i][j], 0, 0, 0);
                ar[i][j] = __builtin_amdgcn_mfma_f32_16x16x32_bf16(
                    af[i], br4[j], ar[i][j], 0, 0, 0);
            }
    }

    // Epilogue 1: kv & r stores. C/D layout: col = lane&15, row = quad*4+reg.
#pragma unroll
    for (int i = 0; i < 4; i++)
#pragma unroll
        for (int j = 0; j < 2; j++)
#pragma unroll
            for (int r = 0; r < 4; r++) {
                const int row = row0 + wr * 64 + i * 16 + kq * 4 + r;
                const int col = e0 + wc * 32 + j * 16 + lrow;
                const size_t o = (size_t)row * DIMD + col;
                Okv[o] = f2b(ak[i][j][r] * av[i][j][r]);
                Or[o]  = f2b(1.f / (1.f + __expf(-ar[i][j][r])));
            }

    // Epilogue 2: per-chunk weighted sum  s(d) = sum_row decay^(63-row) k*v.
    // Lane holds 16 rows of its chunk; reduce across kq quads via shfl_xor.
#pragma unroll
    for (int j = 0; j < 2; j++) {
        const int col = e0 + wc * 32 + j * 16 + lrow;
        const float w = -__expf(td[col]);
        float s = 0.f;
#pragma unroll
        for (int i = 0; i < 4; i++)
#pragma unroll
            for (int r = 0; r < 4; r++) {
                const int rl = i * 16 + kq * 4 + r;           // 0..63
                s += __expf(w * (float)(63 - rl)) * ak[i][j][r] * av[i][j][r];
            }
        s += __shfl_xor(s, 16);
        s += __shfl_xor(s, 32);
        if (kq == 0) {
            const int gchunk = (row0 >> 6) + wr;              // global chunk id
            cs[(size_t)gchunk * DIMD + col] = s;
        }
    }
}

// ---------------------------------------------------------------------------
// Final GEMM: C[n,e] = sum_d A[n,d] * W[e,d], f32 out. (m97 structure)
// ---------------------------------------------------------------------------
__global__ __launch_bounds__(256, 2)
void gemm_bt(const ushort_t* __restrict__ A,
             const ushort_t* __restrict__ W,
             float* __restrict__ Of)
{
    __shared__ __align__(16) ushort_t As[BM * BK];
    __shared__ __align__(16) ushort_t Bs[BN * BK];

    const int tid  = threadIdx.x;
    const int lane = tid & 63;
    const int wv   = tid >> 6;
    const int wr   = wv >> 1;
    const int wc   = wv & 1;
    const int lrow = lane & 15;
    const int kq   = lane >> 4;

    const int row0 = blockIdx.x * BM;
    const int e0   = blockIdx.y * BN;

    f32x4 acc[4][4];
#pragma unroll
    for (int i = 0; i < 4; i++)
#pragma unroll
        for (int j = 0; j < 4; j++)
            acc[i][j] = f32x4{0.f, 0.f, 0.f, 0.f};

    for (int kt = 0; kt < DIMD / BK; ++kt) {
        const int k0 = kt * BK;

        __syncthreads();

#pragma unroll
        for (int it = 0; it < 2; ++it) {
            const int chunk = tid + it * 256;
            const int r = chunk >> 2;
            const int c = (chunk & 3) << 3;
            const ushort_t* ga = A + (size_t)(row0 + r) * DIMD + k0 + c;
            const ushort_t* gb = W + (size_t)(e0 + r) * DIMD + k0 + c;
            __builtin_amdgcn_global_load_lds(
                (__attribute__((address_space(1))) void*)ga,
                (__attribute__((address_space(3))) void*)((char*)As + chunk * 16),
                16, 0, 0);
            __builtin_amdgcn_global_load_lds(
                (__attribute__((address_space(1))) void*)gb,
                (__attribute__((address_space(3))) void*)((char*)Bs + chunk * 16),
                16, 0, 0);
        }

        __syncthreads();

        bf16x8 af[4], bfr[4];
#pragma unroll
        for (int i = 0; i < 4; i++)
            af[i] = *(const bf16x8*)(As + (wr * 64 + i * 16 + lrow) * BK + kq * 8);
#pragma unroll
        for (int j = 0; j < 4; j++)
            bfr[j] = *(const bf16x8*)(Bs + (wc * 64 + j * 16 + lrow) * BK + kq * 8);

#pragma unroll
        for (int i = 0; i < 4; i++)
#pragma unroll
            for (int j = 0; j < 4; j++)
                acc[i][j] = __builtin_amdgcn_mfma_f32_16x16x32_bf16(
                    af[i], bfr[j], acc[i][j], 0, 0, 0);
    }

#pragma unroll
    for (int i = 0; i < 4; i++)
#pragma unroll
        for (int j = 0; j < 4; j++)
#pragma unroll
            for (int r = 0; r < 4; r++) {
                const int row = row0 + wr * 64 + i * 16 + kq * 4 + r;
                const int col = e0 + wc * 64 + j * 16 + lrow;
                Of[(size_t)row * DIMD + col] = acc[i][j][r];
            }
}

// ---------------------------------------------------------------------------
// Scan across chunks, register-resident. Thread per (b, d).
// Replaces cs[c] with the incoming state for chunk c.
// ---------------------------------------------------------------------------
__global__ __launch_bounds__(256)
void chunk_scan(float* __restrict__ cs, const float* __restrict__ td)
{
    const int idx = blockIdx.x * 256 + threadIdx.x;  // 4096 threads
    const int d = idx & (DIMD - 1);
    const int b = idx >> 10;

    const float w      = -__expf(td[d]);
    const float decayL = __expf(w * (float)CHUNK);

    float v[NCHUNK];
    const size_t base = ((size_t)b * NCHUNK) * DIMD + d;
#pragma unroll
    for (int c = 0; c < NCHUNK; c++)
        v[c] = cs[base + (size_t)c * DIMD];

    float st = 0.f;
#pragma unroll
    for (int c = 0; c < NCHUNK; c++) {
        const float sc = v[c];
        v[c] = st;
        st = decayL * st + sc;
    }

#pragma unroll
    for (int c = 0; c < NCHUNK; c++)
        cs[base + (size_t)c * DIMD] = v[c];
}

// ---------------------------------------------------------------------------
// Emit: out_pre = r*(state + eu*kv); state = decay*state + kv. 8 d's/thread.
// ---------------------------------------------------------------------------
__global__ __launch_bounds__(256)
void emit(const ushort_t* __restrict__ kvb, const ushort_t* __restrict__ rb,
          const float* __restrict__ td, const float* __restrict__ tf,
          const float* __restrict__ cs, ushort_t* __restrict__ op)
{
    const int t  = blockIdx.x * 256 + threadIdx.x;   // 32768 threads
    const int d0 = (t & (DIMD / 8 - 1)) * 8;
    const int bc = t >> 7;
    const int c  = bc & (NCHUNK - 1);
    const int b  = bc >> 6;

    float decay[8], eu[8], st[8];
#pragma unroll
    for (int j = 0; j < 8; j++) {
        decay[j] = __expf(-__expf(td[d0 + j]));
        eu[j]    = __expf(tf[d0 + j]);
    }
    const float* csp = cs + ((size_t)bc * DIMD + d0);
    const float4 s0 = *(const float4*)csp;
    const float4 s1 = *(const float4*)(csp + 4);
    st[0] = s0.x; st[1] = s0.y; st[2] = s0.z; st[3] = s0.w;
    st[4] = s1.x; st[5] = s1.y; st[6] = s1.z; st[7] = s1.w;

    size_t off = ((size_t)b * SEQ + (size_t)c * CHUNK) * DIMD + d0;
#pragma unroll 8
    for (int i = 0; i < CHUNK; i++) {
        const u16x8 kv8 = *(const u16x8*)(kvb + off);
        const u16x8 r8  = *(const u16x8*)(rb + off);
        u16x8 o8;
#pragma unroll
        for (int j = 0; j < 8; j++) {
            const float kv = b2f(kv8[j]);
            o8[j] = f2b(b2f(r8[j]) * (st[j] + eu[j] * kv));
            st[j] = decay[j] * st[j] + kv;
        }
        *(u16x8*)(op + off) = o8;
        off += DIMD;
    }
}

// ---------------------------------------------------------------------------
// ws: xb/pbuf 32 MiB + weights 8 MiB + cs 1 MiB = 41 MiB.
// d_out (64 MiB f32) doubles as kvb+rb scratch (dead before final GEMM).
// ---------------------------------------------------------------------------
extern "C" void kernel_launch(void* const* d_in, const int* in_sizes, int n_in,
                              void* d_out, int out_size, void* d_ws, size_t ws_size,
                              hipStream_t stream)
{
    const float* x  = (const float*)d_in[0];
    const float* Wk = (const float*)d_in[1];
    const float* Wv = (const float*)d_in[2];
    const float* Wr = (const float*)d_in[3];
    const float* Wo = (const float*)d_in[4];
    const float* td = (const float*)d_in[5];
    const float* tf = (const float*)d_in[6];

    ushort_t* xb  = (ushort_t*)d_ws;                       // 32 MiB; reused as pbuf
    ushort_t* Wb  = xb + (size_t)NTOK * DIMD;              // 8 MiB (4 matrices)
    ushort_t* Wkb = Wb;
    ushort_t* Wvb = Wb + (size_t)DIMD * DIMD;
    ushort_t* Wrb = Wb + 2 * (size_t)DIMD * DIMD;
    ushort_t* Wob = Wb + 3 * (size_t)DIMD * DIMD;
    float*    cs  = (float*)(Wb + 4 * (size_t)DIMD * DIMD); // 1 MiB
    ushort_t* pbuf = xb;

    ushort_t* kvb = (ushort_t*)d_out;                      // 32 MiB scratch
    ushort_t* rb  = kvb + (size_t)NTOK * DIMD;             // 32 MiB scratch
    float*    out = (float*)d_out;

    // 0) conversions
    conv_f2b<<<NTOK * DIMD / 8 / 256, 256, 0, stream>>>(x, xb, NTOK * DIMD / 8);
    conv_w<<<dim3(DIMD * DIMD / 8 / 256, 4), 256, 0, stream>>>(Wk, Wv, Wr, Wo, Wb);

    // 1) fused kv & r projections + per-chunk aggregates
    gemm_kvr<<<dim3(NTOK / BM, DIMD / BNF), 256, 0, stream>>>(
        xb, Wkb, Wvb, Wrb, td, kvb, rb, cs);

    // 2) scan over chunk boundaries
    chunk_scan<<<BATCH * DIMD / 256, 256, 0, stream>>>(cs, td);

    // 3) out_pre -> pbuf (xb region)
    emit<<<BATCH * NCHUNK * (DIMD / 8) / 256, 256, 0, stream>>>(
        kvb, rb, td, tf, cs, pbuf);

    // 4) out = out_pre @ Wo^T (f32 epilogue, overwrites d_out)
    gemm_bt<<<dim3(NTOK / BM, DIMD / BN), 256, 0, stream>>>(pbuf, Wob, out);
}